// Round 2
// baseline (107.406 us; speedup 1.0000x reference)
//
#include <hip/hip_runtime.h>
#include <hip/hip_bf16.h>
#include <math.h>

typedef __bf16 bf16x8 __attribute__((ext_vector_type(8)));
typedef float  f32x4  __attribute__((ext_vector_type(4)));

#define MFMA16(a,b,c) __builtin_amdgcn_mfma_f32_16x16x32_bf16(a,b,c,0,0,0)

__device__ __forceinline__ float gelu_exact(float x){
    return 0.5f * x * (1.0f + erff(x * 0.7071067811865476f));
}

// ---------- K0: transpose f32 [K][N] -> bf16 [N][K] ----------
__global__ void transp_bf16(const float* __restrict__ src, __bf16* __restrict__ dst,
                            int K, int N){
    int k0 = blockIdx.x * 8;
    int n  = threadIdx.x;
    if (n >= N) return;
    bf16x8 v;
#pragma unroll
    for (int r = 0; r < 8; ++r)
        v[r] = (__bf16)src[(size_t)(k0 + r) * N + n];
    *(bf16x8*)&dst[(size_t)n * K + k0] = v;
}

// ---------- K1: H1 = gelu(LN(X @ W1 + b1)) , bf16 out ----------
// M=16384, K=2048, N=256. BM=64, BN=256, BK=64.
// 512 thr = 8 waves (2 in M x 4 in N), wave tile 32x64.
// A (X, f32->bf16) staged in LDS (16 KiB dbuf); B (W1T) direct global->reg dbuf (L2-resident).
__global__ __launch_bounds__(512) void gemm1_ln_gelu(
    const float* __restrict__ X, const __bf16* __restrict__ W1T,
    const float* __restrict__ b1, const float* __restrict__ g1,
    const float* __restrict__ be1, __bf16* __restrict__ H1)
{
    __shared__ __bf16 lA[2][64*64];    // XOR-swizzled rows of 64 bf16
    __shared__ float  redS[64][4];
    __shared__ float  redQ[64][4];

    const int tid  = threadIdx.x;
    const int wid  = tid >> 6;
    const int lane = tid & 63;
    const int l15  = lane & 15;
    const int lg   = lane >> 4;
    const int wm   = wid >> 2;       // 0..1
    const int wn   = wid & 3;        // 0..3
    const int mBase = blockIdx.x * 64;

    // A staging: 512 threads cover 64 rows x 64 k, 8 f32 each
    const int sRow = tid >> 3;                 // 0..63
    const int sC8  = (tid & 7) * 8;            // 0..56
    const int sDst = sRow * 64 + (sC8 ^ ((sRow & 7) << 3));
    const float* aSrc = X + (size_t)(mBase + sRow) * 2048 + sC8;

    // B per-wave direct pointers: col = wn*64 + n*16 + l15, k offset lg*8
    const __bf16* bP0 = W1T + (size_t)(wn*64 +  0 + l15) * 2048 + lg*8;
    const __bf16* bP1 = W1T + (size_t)(wn*64 + 16 + l15) * 2048 + lg*8;
    const __bf16* bP2 = W1T + (size_t)(wn*64 + 32 + l15) * 2048 + lg*8;
    const __bf16* bP3 = W1T + (size_t)(wn*64 + 48 + l15) * 2048 + lg*8;

    f32x4 acc[2][4] = {};
    bf16x8 fB0[8], fB1[8];

#define LOADB(FB, S)                                                        \
    {                                                                       \
        FB[0] = *(const bf16x8*)(bP0 + (S)*64);                             \
        FB[1] = *(const bf16x8*)(bP1 + (S)*64);                             \
        FB[2] = *(const bf16x8*)(bP2 + (S)*64);                             \
        FB[3] = *(const bf16x8*)(bP3 + (S)*64);                             \
        FB[4] = *(const bf16x8*)(bP0 + (S)*64 + 32);                        \
        FB[5] = *(const bf16x8*)(bP1 + (S)*64 + 32);                        \
        FB[6] = *(const bf16x8*)(bP2 + (S)*64 + 32);                        \
        FB[7] = *(const bf16x8*)(bP3 + (S)*64 + 32);                        \
    }

#define LOADA(A0, A1, S)                                                    \
    {                                                                       \
        A0 = *(const float4*)(aSrc + (S)*64);                               \
        A1 = *(const float4*)(aSrc + (S)*64 + 4);                           \
    }

#define WRITEA(BUF, A0, A1)                                                 \
    {                                                                       \
        bf16x8 v;                                                           \
        v[0]=(__bf16)A0.x; v[1]=(__bf16)A0.y; v[2]=(__bf16)A0.z;            \
        v[3]=(__bf16)A0.w; v[4]=(__bf16)A1.x; v[5]=(__bf16)A1.y;            \
        v[6]=(__bf16)A1.z; v[7]=(__bf16)A1.w;                               \
        *(bf16x8*)&lA[BUF][sDst] = v;                                       \
    }

#define COMPUTE(BUF, FB)                                                    \
    {                                                                       \
        _Pragma("unroll")                                                   \
        for (int kk = 0; kk < 2; ++kk){                                     \
            const int kcol = kk*32 + lg*8;                                  \
            const int swz  = kcol ^ ((l15 & 7) << 3);                       \
            const int r0   = wm*32 + l15;                                   \
            bf16x8 av0 = *(const bf16x8*)&lA[BUF][ r0      *64 + swz];      \
            bf16x8 av1 = *(const bf16x8*)&lA[BUF][(r0+16)  *64 + swz];      \
            _Pragma("unroll")                                               \
            for (int n = 0; n < 4; ++n){                                    \
                acc[0][n] = MFMA16(av0, FB[kk*4+n], acc[0][n]);             \
                acc[1][n] = MFMA16(av1, FB[kk*4+n], acc[1][n]);             \
            }                                                               \
        }                                                                   \
    }

    // prologue: stage step 0
    {
        float4 a0, a1;
        LOADA(a0, a1, 0);
        LOADB(fB0, 0);
        WRITEA(0, a0, a1);
    }
    __syncthreads();

    for (int it = 0; it < 16; ++it){
        const int s = 2*it;
        // even step: compute (lA0, fB0); prefetch s+1
        float4 a0, a1;
        LOADA(a0, a1, s+1);       // issue A first (oldest) ...
        LOADB(fB1, s+1);          // ... then B, so A's wait leaves B pipelined
        COMPUTE(0, fB0);
        WRITEA(1, a0, a1);
        __syncthreads();
        // odd step: compute (lA1, fB1); prefetch s+2
        if (it < 15){
            LOADA(a0, a1, s+2);
            LOADB(fB0, s+2);
        }
        COMPUTE(1, fB1);
        if (it < 15){
            WRITEA(0, a0, a1);
        }
        __syncthreads();
    }

    // ---- epilogue: +b1, LayerNorm(256), gelu, store bf16 ----
    float bias_[4], g1_[4], be_[4];
#pragma unroll
    for (int n = 0; n < 4; ++n){
        int col = wn*64 + n*16 + l15;
        bias_[n] = b1[col]; g1_[n] = g1[col]; be_[n] = be1[col];
    }
#pragma unroll
    for (int m = 0; m < 2; ++m)
#pragma unroll
        for (int n = 0; n < 4; ++n)
#pragma unroll
            for (int r = 0; r < 4; ++r)
                acc[m][n][r] += bias_[n];

#pragma unroll
    for (int m = 0; m < 2; ++m)
#pragma unroll
        for (int r = 0; r < 4; ++r){
            float s = 0.f, q = 0.f;
#pragma unroll
            for (int n = 0; n < 4; ++n){ float v = acc[m][n][r]; s += v; q += v*v; }
#pragma unroll
            for (int off = 1; off <= 8; off <<= 1){
                s += __shfl_xor(s, off, 64);
                q += __shfl_xor(q, off, 64);
            }
            int row = wm*32 + m*16 + lg*4 + r;
            if (l15 == 0){ redS[row][wn] = s; redQ[row][wn] = q; }
        }
    __syncthreads();

#pragma unroll
    for (int m = 0; m < 2; ++m)
#pragma unroll
        for (int r = 0; r < 4; ++r){
            int row = wm*32 + m*16 + lg*4 + r;
            float su = redS[row][0]+redS[row][1]+redS[row][2]+redS[row][3];
            float qu = redQ[row][0]+redQ[row][1]+redQ[row][2]+redQ[row][3];
            float mu  = su * (1.f/256.f);
            float var = qu * (1.f/256.f) - mu*mu;
            float rs  = rsqrtf(var + 1e-5f);
            size_t base = (size_t)(mBase + row) * 256;
#pragma unroll
            for (int n = 0; n < 4; ++n){
                float x  = acc[m][n][r];
                float xn = (x - mu) * rs * g1_[n] + be_[n];
                H1[base + wn*64 + n*16 + l15] = (__bf16)gelu_exact(xn);
            }
        }
#undef LOADB
#undef LOADA
#undef WRITEA
#undef COMPUTE
}

// ---------- K2: adjusted = softmax((base + 0.1*tanh(W3^T gelu(LN(H1@W2+b2)) + b3))/temp) ----------
// 64 rows/block, 512 thr (8 waves 2x4), whole K=256 and whole W2T in LDS.
__global__ __launch_bounds__(512) void tail_fused(
    const __bf16* __restrict__ H1, const __bf16* __restrict__ W2T,
    const float* __restrict__ b2, const float* __restrict__ g2,
    const float* __restrict__ be2, const float* __restrict__ W3,
    const float* __restrict__ b3, const int* __restrict__ labels,
    const float* __restrict__ temperature, float* __restrict__ ADJ)
{
    __shared__ union { __bf16 lH[64*256]; float h2[64*128]; } u;   // 32KB, reused
    __shared__ __bf16 lW[128*256];                                  // 64KB
    __shared__ float  redS[64][4];
    __shared__ float  redQ[64][4];
    __shared__ float  lw3[256];

    const int tid  = threadIdx.x;
    const int wid  = tid >> 6;
    const int lane = tid & 63;
    const int l15  = lane & 15;
    const int lg   = lane >> 4;
    const int wm   = wid >> 2, wn = wid & 3;
    const int mBase = blockIdx.x * 64;

    {   // stage H1 tile (64x256) and W2T (128x256), both XOR-swizzled
        int r0 = tid >> 5;            // 0..15
        int c8 = (tid & 31) * 8;      // 0..248
        int swz = c8 ^ ((r0 & 7) << 3);
#pragma unroll
        for (int i = 0; i < 4; ++i){
            int row = r0 + i*16;
            bf16x8 v = *(const bf16x8*)&H1[(size_t)(mBase+row)*256 + c8];
            *(bf16x8*)&u.lH[row*256 + swz] = v;
        }
#pragma unroll
        for (int i = 0; i < 8; ++i){
            int row = r0 + i*16;
            bf16x8 v = *(const bf16x8*)&W2T[(size_t)row*256 + c8];
            *(bf16x8*)&lW[row*256 + swz] = v;
        }
        if (tid < 256) lw3[tid] = W3[tid];
    }
    __syncthreads();

    f32x4 acc[2][2] = {};
#pragma unroll
    for (int kk = 0; kk < 8; ++kk){
        const int kcol = kk*32 + lg*8;
        bf16x8 av[2], bv[2];
#pragma unroll
        for (int m = 0; m < 2; ++m){
            int row = wm*32 + m*16 + l15;
            av[m] = *(const bf16x8*)&u.lH[row*256 + (kcol ^ ((row&7)<<3))];
        }
#pragma unroll
        for (int n = 0; n < 2; ++n){
            int row = wn*32 + n*16 + l15;
            bv[n] = *(const bf16x8*)&lW[row*256 + (kcol ^ ((row&7)<<3))];
        }
#pragma unroll
        for (int m = 0; m < 2; ++m)
#pragma unroll
            for (int n = 0; n < 2; ++n)
                acc[m][n] = MFMA16(av[m], bv[n], acc[m][n]);
    }

    float b2_[2], g2_[2], be_[2];
#pragma unroll
    for (int n = 0; n < 2; ++n){
        int col = wn*32 + n*16 + l15;
        b2_[n] = b2[col]; g2_[n] = g2[col]; be_[n] = be2[col];
    }
#pragma unroll
    for (int m = 0; m < 2; ++m)
#pragma unroll
        for (int n = 0; n < 2; ++n)
#pragma unroll
            for (int r = 0; r < 4; ++r)
                acc[m][n][r] += b2_[n];

#pragma unroll
    for (int m = 0; m < 2; ++m)
#pragma unroll
        for (int r = 0; r < 4; ++r){
            float s = 0.f, q = 0.f;
#pragma unroll
            for (int n = 0; n < 2; ++n){ float v = acc[m][n][r]; s += v; q += v*v; }
#pragma unroll
            for (int off = 1; off <= 8; off <<= 1){
                s += __shfl_xor(s, off, 64);
                q += __shfl_xor(q, off, 64);
            }
            int row = wm*32 + m*16 + lg*4 + r;
            if (l15 == 0){ redS[row][wn] = s; redQ[row][wn] = q; }
        }
    __syncthreads();   // also: all lH reads done -> safe to overwrite with h2

#pragma unroll
    for (int m = 0; m < 2; ++m)
#pragma unroll
        for (int r = 0; r < 4; ++r){
            int row = wm*32 + m*16 + lg*4 + r;
            float su = redS[row][0]+redS[row][1]+redS[row][2]+redS[row][3];
            float qu = redQ[row][0]+redQ[row][1]+redQ[row][2]+redQ[row][3];
            float mu  = su * (1.f/128.f);
            float var = qu * (1.f/128.f) - mu*mu;
            float rs  = rsqrtf(var + 1e-5f);
#pragma unroll
            for (int n = 0; n < 2; ++n){
                int col = wn*32 + n*16 + l15;
                float x = acc[m][n][r];
                float h = gelu_exact((x - mu)*rs*g2_[n] + be_[n]);
                u.h2[row*128 + (col ^ (row & 31))] = h;
            }
        }
    __syncthreads();

    if (tid < 64){
        const int row = tid;
        const int g = mBase + row;
        float a0 = b3[0], a1 = b3[1];
        for (int k = 0; k < 128; ++k){
            float v = u.h2[row*128 + (k ^ (row & 31))];
            a0 += v * lw3[2*k];
            a1 += v * lw3[2*k+1];
        }
        float t = fmaxf(temperature[0], 0.1f);
        float adj0 = tanhf(a0) * 0.1f;
        float adj1 = tanhf(a1) * 0.1f;
        bool crit = labels[g] > 0;
        float base0 = crit ? 0.25f : 0.75f;
        float base1 = crit ? 0.75f : 0.25f;
        float L0 = (base0 + adj0) / t, L1 = (base1 + adj1) / t;
        float mm = fmaxf(L0, L1);
        float e0 = expf(L0 - mm), e1 = expf(L1 - mm);
        float inv = 1.f / (e0 + e1);
        ADJ[(size_t)g*2    ] = e0 * inv;
        ADJ[(size_t)g*2 + 1] = e1 * inv;
    }
}

// ---------- K3: EMA as a 128-tap truncated convolution (0.9^128 ~ 1.4e-6) ----------
__global__ void ema_kernel(const float* __restrict__ ADJ, float* __restrict__ out)
{
    __shared__ float wtab[128];
    __shared__ float abuf[384*2];
    const int b     = blockIdx.x >> 2;
    const int chunk = blockIdx.x & 3;
    const int c0    = chunk * 256;
    const int tid   = threadIdx.x;
    if (tid < 128) wtab[tid] = powf(0.9f, (float)tid);
    for (int idx = tid; idx < 768; idx += 256){
        int tt = c0 - 128 + (idx >> 1);
        int cc = idx & 1;
        abuf[idx] = (tt >= 0) ? ADJ[((size_t)b*1024 + tt)*2 + cc] : 0.f;
    }
    __syncthreads();
#pragma unroll
    for (int i = 0; i < 2; ++i){
        int item = tid + i*256;
        int tl = item >> 1, cc = item & 1;
        int t = c0 + tl;
        int kmax = min(t, 127);
        float sum = 0.f;
        for (int k = 0; k <= kmax; ++k){
            float coef = (t - k == 0) ? wtab[k] : 0.1f * wtab[k];
            sum += coef * abuf[(tl - k + 128)*2 + cc];
        }
        out[((size_t)b*1024 + t)*2 + cc] = sum;
    }
}

extern "C" void kernel_launch(void* const* d_in, const int* in_sizes, int n_in,
                              void* d_out, int out_size, void* d_ws, size_t ws_size,
                              hipStream_t stream)
{
    const int*   labels = (const int*)  d_in[0];
    const float* X      = (const float*)d_in[1];
    const float* W1     = (const float*)d_in[2];
    const float* b1     = (const float*)d_in[3];
    const float* g1     = (const float*)d_in[4];
    const float* be1    = (const float*)d_in[5];
    const float* W2     = (const float*)d_in[6];
    const float* b2     = (const float*)d_in[7];
    const float* g2     = (const float*)d_in[8];
    const float* be2    = (const float*)d_in[9];
    const float* W3     = (const float*)d_in[10];
    const float* b3     = (const float*)d_in[11];
    const float* temp   = (const float*)d_in[12];
    float* out = (float*)d_out;

    char* ws = (char*)d_ws;
    __bf16* W1T = (__bf16*)(ws);                 // 256 x 2048 bf16  (1 MiB)
    __bf16* W2T = (__bf16*)(ws + 1048576);       // 128 x 256  bf16  (64 KiB)
    __bf16* H1  = (__bf16*)(ws + 1114112);       // 16384 x 256 bf16 (8 MiB)
    float*  ADJ = (float*)(ws + 9502720);        // 16384 x 2 f32    (128 KiB)

    transp_bf16<<<256, 256, 0, stream>>>(W1, W1T, 2048, 256);
    transp_bf16<<<32,  256, 0, stream>>>(W2, W2T, 256, 128);
    gemm1_ln_gelu<<<256, 512, 0, stream>>>(X, W1T, b1, g1, be1, H1);
    tail_fused<<<256, 512, 0, stream>>>(H1, W2T, b2, g2, be2, W3, b3, labels, temp, ADJ);
    ema_kernel<<<64, 256, 0, stream>>>(ADJ, out);
}

// Round 3
// 107.263 us; speedup vs baseline: 1.0013x; 1.0013x over previous
//
#include <hip/hip_runtime.h>
#include <hip/hip_bf16.h>
#include <math.h>

typedef __bf16 bf16x8 __attribute__((ext_vector_type(8)));
typedef float  f32x4  __attribute__((ext_vector_type(4)));

#define MFMA16(a,b,c) __builtin_amdgcn_mfma_f32_16x16x32_bf16(a,b,c,0,0,0)

__device__ __forceinline__ float gelu_exact(float x){
    return 0.5f * x * (1.0f + erff(x * 0.7071067811865476f));
}

// ---------- K0: transpose f32 [K][N] -> bf16 [N][K] ----------
__global__ void transp_bf16(const float* __restrict__ src, __bf16* __restrict__ dst,
                            int K, int N){
    int k0 = blockIdx.x * 8;
    int n  = threadIdx.x;
    if (n >= N) return;
    bf16x8 v;
#pragma unroll
    for (int r = 0; r < 8; ++r)
        v[r] = (__bf16)src[(size_t)(k0 + r) * N + n];
    *(bf16x8*)&dst[(size_t)n * K + k0] = v;
}

// ---------- K1: H1 = gelu(LN(X @ W1 + b1)) , bf16 out ----------
// M=16384, K=2048, N=256. BM=64, BN=256, BK=64.
// 512 thr = 8 waves (2 in M x 4 in N), wave tile 32x64.
// A (X, f32->bf16) staged in LDS (16 KiB dbuf); B (W1T) direct global->reg dbuf (L2-resident).
// __launch_bounds__(512, 1): allow up to 256 VGPRs so fB0/fB1 stay register-resident
// (R2 showed VGPR=60 => compiler destroyed the register double-buffer).
__global__ __launch_bounds__(512, 1) void gemm1_ln_gelu(
    const float* __restrict__ X, const __bf16* __restrict__ W1T,
    const float* __restrict__ b1, const float* __restrict__ g1,
    const float* __restrict__ be1, __bf16* __restrict__ H1)
{
    __shared__ __bf16 lA[2][64*64];    // XOR-swizzled rows of 64 bf16
    __shared__ float  redS[64][4];
    __shared__ float  redQ[64][4];

    const int tid  = threadIdx.x;
    const int wid  = tid >> 6;
    const int lane = tid & 63;
    const int l15  = lane & 15;
    const int lg   = lane >> 4;
    const int wm   = wid >> 2;       // 0..1
    const int wn   = wid & 3;        // 0..3
    const int mBase = blockIdx.x * 64;

    // A staging: 512 threads cover 64 rows x 64 k, 8 f32 each
    const int sRow = tid >> 3;                 // 0..63
    const int sC8  = (tid & 7) * 8;            // 0..56
    const int sDst = sRow * 64 + (sC8 ^ ((sRow & 7) << 3));
    const float* aSrc = X + (size_t)(mBase + sRow) * 2048 + sC8;

    // B per-wave direct pointers: col = wn*64 + n*16 + l15, k offset lg*8
    const __bf16* bP0 = W1T + (size_t)(wn*64 +  0 + l15) * 2048 + lg*8;
    const __bf16* bP1 = W1T + (size_t)(wn*64 + 16 + l15) * 2048 + lg*8;
    const __bf16* bP2 = W1T + (size_t)(wn*64 + 32 + l15) * 2048 + lg*8;
    const __bf16* bP3 = W1T + (size_t)(wn*64 + 48 + l15) * 2048 + lg*8;

    f32x4 acc[2][4] = {};
    bf16x8 fB0[8], fB1[8];

#define LOADB(FB, S)                                                        \
    {                                                                       \
        FB[0] = *(const bf16x8*)(bP0 + (S)*64);                             \
        FB[1] = *(const bf16x8*)(bP1 + (S)*64);                             \
        FB[2] = *(const bf16x8*)(bP2 + (S)*64);                             \
        FB[3] = *(const bf16x8*)(bP3 + (S)*64);                             \
        FB[4] = *(const bf16x8*)(bP0 + (S)*64 + 32);                        \
        FB[5] = *(const bf16x8*)(bP1 + (S)*64 + 32);                        \
        FB[6] = *(const bf16x8*)(bP2 + (S)*64 + 32);                        \
        FB[7] = *(const bf16x8*)(bP3 + (S)*64 + 32);                        \
    }

#define LOADA(A0, A1, S)                                                    \
    {                                                                       \
        A0 = *(const float4*)(aSrc + (S)*64);                               \
        A1 = *(const float4*)(aSrc + (S)*64 + 4);                           \
    }

#define WRITEA(BUF, A0, A1)                                                 \
    {                                                                       \
        bf16x8 v;                                                           \
        v[0]=(__bf16)A0.x; v[1]=(__bf16)A0.y; v[2]=(__bf16)A0.z;            \
        v[3]=(__bf16)A0.w; v[4]=(__bf16)A1.x; v[5]=(__bf16)A1.y;            \
        v[6]=(__bf16)A1.z; v[7]=(__bf16)A1.w;                               \
        *(bf16x8*)&lA[BUF][sDst] = v;                                       \
    }

#define COMPUTE(BUF, FB)                                                    \
    {                                                                       \
        _Pragma("unroll")                                                   \
        for (int kk = 0; kk < 2; ++kk){                                     \
            const int kcol = kk*32 + lg*8;                                  \
            const int swz  = kcol ^ ((l15 & 7) << 3);                       \
            const int r0   = wm*32 + l15;                                   \
            bf16x8 av0 = *(const bf16x8*)&lA[BUF][ r0      *64 + swz];      \
            bf16x8 av1 = *(const bf16x8*)&lA[BUF][(r0+16)  *64 + swz];      \
            _Pragma("unroll")                                               \
            for (int n = 0; n < 4; ++n){                                    \
                acc[0][n] = MFMA16(av0, FB[kk*4+n], acc[0][n]);             \
                acc[1][n] = MFMA16(av1, FB[kk*4+n], acc[1][n]);             \
            }                                                               \
        }                                                                   \
    }

    // prologue: stage step 0
    {
        float4 a0, a1;
        LOADA(a0, a1, 0);
        LOADB(fB0, 0);
        WRITEA(0, a0, a1);
    }
    __syncthreads();

    for (int it = 0; it < 16; ++it){
        const int s = 2*it;
        // even step: compute (lA0, fB0); prefetch s+1
        float4 a0, a1;
        LOADA(a0, a1, s+1);       // issue A first (oldest) ...
        LOADB(fB1, s+1);          // ... then B, so A's wait leaves B pipelined
        COMPUTE(0, fB0);
        WRITEA(1, a0, a1);
        __syncthreads();
        // odd step: compute (lA1, fB1); prefetch s+2
        if (it < 15){
            LOADA(a0, a1, s+2);
            LOADB(fB0, s+2);
        }
        COMPUTE(1, fB1);
        if (it < 15){
            WRITEA(0, a0, a1);
        }
        __syncthreads();
    }

    // ---- epilogue: +b1, LayerNorm(256), gelu, store bf16 ----
    float bias_[4], g1_[4], be_[4];
#pragma unroll
    for (int n = 0; n < 4; ++n){
        int col = wn*64 + n*16 + l15;
        bias_[n] = b1[col]; g1_[n] = g1[col]; be_[n] = be1[col];
    }
#pragma unroll
    for (int m = 0; m < 2; ++m)
#pragma unroll
        for (int n = 0; n < 4; ++n)
#pragma unroll
            for (int r = 0; r < 4; ++r)
                acc[m][n][r] += bias_[n];

#pragma unroll
    for (int m = 0; m < 2; ++m)
#pragma unroll
        for (int r = 0; r < 4; ++r){
            float s = 0.f, q = 0.f;
#pragma unroll
            for (int n = 0; n < 4; ++n){ float v = acc[m][n][r]; s += v; q += v*v; }
#pragma unroll
            for (int off = 1; off <= 8; off <<= 1){
                s += __shfl_xor(s, off, 64);
                q += __shfl_xor(q, off, 64);
            }
            int row = wm*32 + m*16 + lg*4 + r;
            if (l15 == 0){ redS[row][wn] = s; redQ[row][wn] = q; }
        }
    __syncthreads();

#pragma unroll
    for (int m = 0; m < 2; ++m)
#pragma unroll
        for (int r = 0; r < 4; ++r){
            int row = wm*32 + m*16 + lg*4 + r;
            float su = redS[row][0]+redS[row][1]+redS[row][2]+redS[row][3];
            float qu = redQ[row][0]+redQ[row][1]+redQ[row][2]+redQ[row][3];
            float mu  = su * (1.f/256.f);
            float var = qu * (1.f/256.f) - mu*mu;
            float rs  = rsqrtf(var + 1e-5f);
            size_t base = (size_t)(mBase + row) * 256;
#pragma unroll
            for (int n = 0; n < 4; ++n){
                float x  = acc[m][n][r];
                float xn = (x - mu) * rs * g1_[n] + be_[n];
                H1[base + wn*64 + n*16 + l15] = (__bf16)gelu_exact(xn);
            }
        }
#undef LOADB
#undef LOADA
#undef WRITEA
#undef COMPUTE
}

// ---------- K2: adjusted = softmax((base + 0.1*tanh(W3^T gelu(LN(H1@W2+b2)) + b3))/temp) ----------
// 64 rows/block, 512 thr (8 waves 2x4), whole K=256 and whole W2T in LDS.
__global__ __launch_bounds__(512) void tail_fused(
    const __bf16* __restrict__ H1, const __bf16* __restrict__ W2T,
    const float* __restrict__ b2, const float* __restrict__ g2,
    const float* __restrict__ be2, const float* __restrict__ W3,
    const float* __restrict__ b3, const int* __restrict__ labels,
    const float* __restrict__ temperature, float* __restrict__ ADJ)
{
    __shared__ union { __bf16 lH[64*256]; float h2[64*128]; } u;   // 32KB, reused
    __shared__ __bf16 lW[128*256];                                  // 64KB
    __shared__ float  redS[64][4];
    __shared__ float  redQ[64][4];
    __shared__ float  lw3[256];

    const int tid  = threadIdx.x;
    const int wid  = tid >> 6;
    const int lane = tid & 63;
    const int l15  = lane & 15;
    const int lg   = lane >> 4;
    const int wm   = wid >> 2, wn = wid & 3;
    const int mBase = blockIdx.x * 64;

    {   // stage H1 tile (64x256) and W2T (128x256), both XOR-swizzled
        int r0 = tid >> 5;            // 0..15
        int c8 = (tid & 31) * 8;      // 0..248
        int swz = c8 ^ ((r0 & 7) << 3);
#pragma unroll
        for (int i = 0; i < 4; ++i){
            int row = r0 + i*16;
            bf16x8 v = *(const bf16x8*)&H1[(size_t)(mBase+row)*256 + c8];
            *(bf16x8*)&u.lH[row*256 + swz] = v;
        }
#pragma unroll
        for (int i = 0; i < 8; ++i){
            int row = r0 + i*16;
            bf16x8 v = *(const bf16x8*)&W2T[(size_t)row*256 + c8];
            *(bf16x8*)&lW[row*256 + swz] = v;
        }
        if (tid < 256) lw3[tid] = W3[tid];
    }
    __syncthreads();

    f32x4 acc[2][2] = {};
#pragma unroll
    for (int kk = 0; kk < 8; ++kk){
        const int kcol = kk*32 + lg*8;
        bf16x8 av[2], bv[2];
#pragma unroll
        for (int m = 0; m < 2; ++m){
            int row = wm*32 + m*16 + l15;
            av[m] = *(const bf16x8*)&u.lH[row*256 + (kcol ^ ((row&7)<<3))];
        }
#pragma unroll
        for (int n = 0; n < 2; ++n){
            int row = wn*32 + n*16 + l15;
            bv[n] = *(const bf16x8*)&lW[row*256 + (kcol ^ ((row&7)<<3))];
        }
#pragma unroll
        for (int m = 0; m < 2; ++m)
#pragma unroll
            for (int n = 0; n < 2; ++n)
                acc[m][n] = MFMA16(av[m], bv[n], acc[m][n]);
    }

    float b2_[2], g2_[2], be_[2];
#pragma unroll
    for (int n = 0; n < 2; ++n){
        int col = wn*32 + n*16 + l15;
        b2_[n] = b2[col]; g2_[n] = g2[col]; be_[n] = be2[col];
    }
#pragma unroll
    for (int m = 0; m < 2; ++m)
#pragma unroll
        for (int n = 0; n < 2; ++n)
#pragma unroll
            for (int r = 0; r < 4; ++r)
                acc[m][n][r] += b2_[n];

#pragma unroll
    for (int m = 0; m < 2; ++m)
#pragma unroll
        for (int r = 0; r < 4; ++r){
            float s = 0.f, q = 0.f;
#pragma unroll
            for (int n = 0; n < 2; ++n){ float v = acc[m][n][r]; s += v; q += v*v; }
#pragma unroll
            for (int off = 1; off <= 8; off <<= 1){
                s += __shfl_xor(s, off, 64);
                q += __shfl_xor(q, off, 64);
            }
            int row = wm*32 + m*16 + lg*4 + r;
            if (l15 == 0){ redS[row][wn] = s; redQ[row][wn] = q; }
        }
    __syncthreads();   // also: all lH reads done -> safe to overwrite with h2

#pragma unroll
    for (int m = 0; m < 2; ++m)
#pragma unroll
        for (int r = 0; r < 4; ++r){
            int row = wm*32 + m*16 + lg*4 + r;
            float su = redS[row][0]+redS[row][1]+redS[row][2]+redS[row][3];
            float qu = redQ[row][0]+redQ[row][1]+redQ[row][2]+redQ[row][3];
            float mu  = su * (1.f/128.f);
            float var = qu * (1.f/128.f) - mu*mu;
            float rs  = rsqrtf(var + 1e-5f);
#pragma unroll
            for (int n = 0; n < 2; ++n){
                int col = wn*32 + n*16 + l15;
                float x = acc[m][n][r];
                float h = gelu_exact((x - mu)*rs*g2_[n] + be_[n]);
                u.h2[row*128 + (col ^ (row & 31))] = h;
            }
        }
    __syncthreads();

    if (tid < 64){
        const int row = tid;
        const int g = mBase + row;
        float a0 = b3[0], a1 = b3[1];
        for (int k = 0; k < 128; ++k){
            float v = u.h2[row*128 + (k ^ (row & 31))];
            a0 += v * lw3[2*k];
            a1 += v * lw3[2*k+1];
        }
        float t = fmaxf(temperature[0], 0.1f);
        float adj0 = tanhf(a0) * 0.1f;
        float adj1 = tanhf(a1) * 0.1f;
        bool crit = labels[g] > 0;
        float base0 = crit ? 0.25f : 0.75f;
        float base1 = crit ? 0.75f : 0.25f;
        float L0 = (base0 + adj0) / t, L1 = (base1 + adj1) / t;
        float mm = fmaxf(L0, L1);
        float e0 = expf(L0 - mm), e1 = expf(L1 - mm);
        float inv = 1.f / (e0 + e1);
        ADJ[(size_t)g*2    ] = e0 * inv;
        ADJ[(size_t)g*2 + 1] = e1 * inv;
    }
}

// ---------- K3: EMA as a 128-tap truncated convolution (0.9^128 ~ 1.4e-6) ----------
__global__ void ema_kernel(const float* __restrict__ ADJ, float* __restrict__ out)
{
    __shared__ float wtab[128];
    __shared__ float abuf[384*2];
    const int b     = blockIdx.x >> 2;
    const int chunk = blockIdx.x & 3;
    const int c0    = chunk * 256;
    const int tid   = threadIdx.x;
    if (tid < 128) wtab[tid] = powf(0.9f, (float)tid);
    for (int idx = tid; idx < 768; idx += 256){
        int tt = c0 - 128 + (idx >> 1);
        int cc = idx & 1;
        abuf[idx] = (tt >= 0) ? ADJ[((size_t)b*1024 + tt)*2 + cc] : 0.f;
    }
    __syncthreads();
#pragma unroll
    for (int i = 0; i < 2; ++i){
        int item = tid + i*256;
        int tl = item >> 1, cc = item & 1;
        int t = c0 + tl;
        int kmax = min(t, 127);
        float sum = 0.f;
        for (int k = 0; k <= kmax; ++k){
            float coef = (t - k == 0) ? wtab[k] : 0.1f * wtab[k];
            sum += coef * abuf[(tl - k + 128)*2 + cc];
        }
        out[((size_t)b*1024 + t)*2 + cc] = sum;
    }
}

extern "C" void kernel_launch(void* const* d_in, const int* in_sizes, int n_in,
                              void* d_out, int out_size, void* d_ws, size_t ws_size,
                              hipStream_t stream)
{
    const int*   labels = (const int*)  d_in[0];
    const float* X      = (const float*)d_in[1];
    const float* W1     = (const float*)d_in[2];
    const float* b1     = (const float*)d_in[3];
    const float* g1     = (const float*)d_in[4];
    const float* be1    = (const float*)d_in[5];
    const float* W2     = (const float*)d_in[6];
    const float* b2     = (const float*)d_in[7];
    const float* g2     = (const float*)d_in[8];
    const float* be2    = (const float*)d_in[9];
    const float* W3     = (const float*)d_in[10];
    const float* b3     = (const float*)d_in[11];
    const float* temp   = (const float*)d_in[12];
    float* out = (float*)d_out;

    char* ws = (char*)d_ws;
    __bf16* W1T = (__bf16*)(ws);                 // 256 x 2048 bf16  (1 MiB)
    __bf16* W2T = (__bf16*)(ws + 1048576);       // 128 x 256  bf16  (64 KiB)
    __bf16* H1  = (__bf16*)(ws + 1114112);       // 16384 x 256 bf16 (8 MiB)
    float*  ADJ = (float*)(ws + 9502720);        // 16384 x 2 f32    (128 KiB)

    transp_bf16<<<256, 256, 0, stream>>>(W1, W1T, 2048, 256);
    transp_bf16<<<32,  256, 0, stream>>>(W2, W2T, 256, 128);
    gemm1_ln_gelu<<<256, 512, 0, stream>>>(X, W1T, b1, g1, be1, H1);
    tail_fused<<<256, 512, 0, stream>>>(H1, W2T, b2, g2, be2, W3, b3, labels, temp, ADJ);
    ema_kernel<<<64, 256, 0, stream>>>(ADJ, out);
}

// Round 4
// 80.395 us; speedup vs baseline: 1.3360x; 1.3342x over previous
//
#include <hip/hip_runtime.h>
#include <hip/hip_bf16.h>
#include <math.h>

typedef __bf16 bf16x8 __attribute__((ext_vector_type(8)));
typedef float  f32x4  __attribute__((ext_vector_type(4)));

#define MFMA16(a,b,c) __builtin_amdgcn_mfma_f32_16x16x32_bf16(a,b,c,0,0,0)

__device__ __forceinline__ float gelu_exact(float x){
    return 0.5f * x * (1.0f + erff(x * 0.7071067811865476f));
}

__device__ __forceinline__ void gld_lds16(const void* g, void* l){
    __builtin_amdgcn_global_load_lds(
        (const __attribute__((address_space(1))) unsigned int*)g,
        (__attribute__((address_space(3))) unsigned int*)l, 16, 0, 0);
}

// ---------- K0: transpose f32 [K][N] -> bf16 [N][K] ----------
__global__ void transp_bf16(const float* __restrict__ src, __bf16* __restrict__ dst,
                            int K, int N){
    int k0 = blockIdx.x * 8;
    int n  = threadIdx.x;
    if (n >= N) return;
    bf16x8 v;
#pragma unroll
    for (int r = 0; r < 8; ++r)
        v[r] = (__bf16)src[(size_t)(k0 + r) * N + n];
    *(bf16x8*)&dst[(size_t)n * K + k0] = v;
}

// ---------- K1: H1 = gelu(LN(X @ W1 + b1)) , bf16 out ----------
// M=16384, K=2048, N=256. BM=64, BN=256, BK=64. 512 thr = 8 waves (2M x 4N), wave tile 32x64.
// B (W1T): global_load_lds DMA, triple-buffered LDS, pre-swizzled SOURCE addresses
//   (LDS dest must be linear), counted vmcnt so 4 DMAs stay in flight across raw s_barrier.
// A (X): reg-staged f32->bf16, XOR-swizzled ds_write; compiler's auto-wait = vmcnt(4).
__global__ __launch_bounds__(512, 1) void gemm1_ln_gelu(
    const float* __restrict__ X, const __bf16* __restrict__ W1T,
    const float* __restrict__ b1, const float* __restrict__ g1,
    const float* __restrict__ be1, __bf16* __restrict__ H1)
{
    __shared__ __bf16 lA[3][64*64];     // 3 x 8 KB
    __shared__ __bf16 lB[3][256*64];    // 3 x 32 KB
    __shared__ float  redS[64][4];
    __shared__ float  redQ[64][4];

    const int tid  = threadIdx.x;
    const int wid  = tid >> 6;
    const int lane = tid & 63;
    const int l15  = lane & 15;
    const int lg   = lane >> 4;
    const int wm   = wid >> 2;       // 0..1
    const int wn   = wid & 3;        // 0..3
    const int mBase = blockIdx.x * 64;

    // ---- A staging geometry: 512 thr cover 64 rows x 64 k, 8 f32 each ----
    const int sRow = tid >> 3;
    const int sC8  = (tid & 7) * 8;
    const int sDst = sRow * 64 + (sC8 ^ ((sRow & 7) << 3));
    const float* aSrc = X + (size_t)(mBase + sRow) * 2048 + sC8;

    // ---- B staging geometry: 2048 chunks of 16B; wave w, round r, lane ----
    // LDS linear: chunk j at byte j*16. row=j>>3, slot=j&7.
    // Want LDS slot s of row to hold global k-chunk (s ^ (row&7))  [read path XOR].
    const __bf16* bSrc[4];
    int ldsOff[4];
#pragma unroll
    for (int r = 0; r < 4; ++r){
        int j   = wid*256 + r*64 + lane;
        int row = j >> 3;
        int c   = (j & 7) ^ (row & 7);
        bSrc[r] = W1T + (size_t)row * 2048 + c*8;
        ldsOff[r] = __builtin_amdgcn_readfirstlane(wid*4096 + r*1024);  // bytes
    }

    f32x4 acc[2][4] = {};
    float4 a0, a1;

#define LOADA(S) { a0 = *(const float4*)(aSrc + (size_t)(S)*64);            \
                   a1 = *(const float4*)(aSrc + (size_t)(S)*64 + 4); }

#define WRITEA(BUF) {                                                        \
        bf16x8 v;                                                            \
        v[0]=(__bf16)a0.x; v[1]=(__bf16)a0.y; v[2]=(__bf16)a0.z;             \
        v[3]=(__bf16)a0.w; v[4]=(__bf16)a1.x; v[5]=(__bf16)a1.y;             \
        v[6]=(__bf16)a1.z; v[7]=(__bf16)a1.w;                                \
        *(bf16x8*)&lA[BUF][sDst] = v; }

#define STAGEB(BUF, KT) {                                                    \
        char* _lb = (char*)&lB[BUF][0];                                      \
        _Pragma("unroll")                                                    \
        for (int r = 0; r < 4; ++r)                                          \
            gld_lds16(bSrc[r] + (KT)*64, _lb + ldsOff[r]); }

#define COMPUTE(BUF) {                                                       \
        const __bf16* pa = &lA[BUF][0];                                      \
        const __bf16* pb = &lB[BUF][0];                                      \
        _Pragma("unroll")                                                    \
        for (int kk = 0; kk < 2; ++kk){                                      \
            const int kx = (kk*32 + lg*8) ^ ((l15 & 7) << 3);                \
            bf16x8 av0 = *(const bf16x8*)&pa[(wm*32      + l15)*64 + kx];    \
            bf16x8 av1 = *(const bf16x8*)&pa[(wm*32 + 16 + l15)*64 + kx];    \
            bf16x8 bv0 = *(const bf16x8*)&pb[(wn*64      + l15)*64 + kx];    \
            bf16x8 bv1 = *(const bf16x8*)&pb[(wn*64 + 16 + l15)*64 + kx];    \
            bf16x8 bv2 = *(const bf16x8*)&pb[(wn*64 + 32 + l15)*64 + kx];    \
            bf16x8 bv3 = *(const bf16x8*)&pb[(wn*64 + 48 + l15)*64 + kx];    \
            acc[0][0] = MFMA16(av0, bv0, acc[0][0]);                         \
            acc[0][1] = MFMA16(av0, bv1, acc[0][1]);                         \
            acc[0][2] = MFMA16(av0, bv2, acc[0][2]);                         \
            acc[0][3] = MFMA16(av0, bv3, acc[0][3]);                         \
            acc[1][0] = MFMA16(av1, bv0, acc[1][0]);                         \
            acc[1][1] = MFMA16(av1, bv1, acc[1][1]);                         \
            acc[1][2] = MFMA16(av1, bv2, acc[1][2]);                         \
            acc[1][3] = MFMA16(av1, bv3, acc[1][3]);                         \
        } }

    // ---- prologue: stage steps 0 and 1 ----
    LOADA(0);
    __builtin_amdgcn_sched_barrier(0);
    STAGEB(0, 0);
    __builtin_amdgcn_sched_barrier(0);
    WRITEA(0);                                   // compiler waits A0 (vmcnt(4)), B0 stays in flight
    LOADA(1);
    __builtin_amdgcn_sched_barrier(0);
    STAGEB(1, 1);
    __builtin_amdgcn_sched_barrier(0);
    WRITEA(1);                                   // drains B0 + A1 (vmcnt(4)), B1 in flight
    asm volatile("s_waitcnt vmcnt(4) lgkmcnt(0)" ::: "memory");
    __builtin_amdgcn_s_barrier();

    // ---- main loop: compute t, stage t+2; never drain vmcnt to 0 ----
    int bc = 0;
    for (int t = 0; t < 30; ++t){
        int bn = bc + 2; if (bn >= 3) bn -= 3;   // (t+2)%3
        LOADA(t+2);
        __builtin_amdgcn_sched_barrier(0);
        STAGEB(bn, t+2);
        __builtin_amdgcn_sched_barrier(0);
        COMPUTE(bc);
        WRITEA(bn);                              // auto-wait vmcnt(4): drains B(t+1)+A(t+2)
        asm volatile("s_waitcnt vmcnt(4) lgkmcnt(0)" ::: "memory");
        __builtin_amdgcn_s_barrier();
        bc = (bc + 1 == 3) ? 0 : bc + 1;
    }
    COMPUTE(bc);                                 // t=30 (buf 0)
    asm volatile("s_waitcnt vmcnt(0) lgkmcnt(0)" ::: "memory");
    __builtin_amdgcn_s_barrier();
    bc = (bc + 1 == 3) ? 0 : bc + 1;
    COMPUTE(bc);                                 // t=31 (buf 1)

    // ---- epilogue: +b1, LayerNorm(256), gelu, store bf16 ----
    float bias_[4], g1_[4], be_[4];
#pragma unroll
    for (int n = 0; n < 4; ++n){
        int col = wn*64 + n*16 + l15;
        bias_[n] = b1[col]; g1_[n] = g1[col]; be_[n] = be1[col];
    }
#pragma unroll
    for (int m = 0; m < 2; ++m)
#pragma unroll
        for (int n = 0; n < 4; ++n)
#pragma unroll
            for (int r = 0; r < 4; ++r)
                acc[m][n][r] += bias_[n];

#pragma unroll
    for (int m = 0; m < 2; ++m)
#pragma unroll
        for (int r = 0; r < 4; ++r){
            float s = 0.f, q = 0.f;
#pragma unroll
            for (int n = 0; n < 4; ++n){ float v = acc[m][n][r]; s += v; q += v*v; }
#pragma unroll
            for (int off = 1; off <= 8; off <<= 1){
                s += __shfl_xor(s, off, 64);
                q += __shfl_xor(q, off, 64);
            }
            int row = wm*32 + m*16 + lg*4 + r;
            if (l15 == 0){ redS[row][wn] = s; redQ[row][wn] = q; }
        }
    __syncthreads();

#pragma unroll
    for (int m = 0; m < 2; ++m)
#pragma unroll
        for (int r = 0; r < 4; ++r){
            int row = wm*32 + m*16 + lg*4 + r;
            float su = redS[row][0]+redS[row][1]+redS[row][2]+redS[row][3];
            float qu = redQ[row][0]+redQ[row][1]+redQ[row][2]+redQ[row][3];
            float mu  = su * (1.f/256.f);
            float var = qu * (1.f/256.f) - mu*mu;
            float rs  = rsqrtf(var + 1e-5f);
            size_t base = (size_t)(mBase + row) * 256;
#pragma unroll
            for (int n = 0; n < 4; ++n){
                float x  = acc[m][n][r];
                float xn = (x - mu) * rs * g1_[n] + be_[n];
                H1[base + wn*64 + n*16 + l15] = (__bf16)gelu_exact(xn);
            }
        }
#undef LOADA
#undef WRITEA
#undef STAGEB
#undef COMPUTE
}

// ---------- K2: adjusted = softmax((base + 0.1*tanh(W3^T gelu(LN(H1@W2+b2)) + b3))/temp) ----------
__global__ __launch_bounds__(512) void tail_fused(
    const __bf16* __restrict__ H1, const __bf16* __restrict__ W2T,
    const float* __restrict__ b2, const float* __restrict__ g2,
    const float* __restrict__ be2, const float* __restrict__ W3,
    const float* __restrict__ b3, const int* __restrict__ labels,
    const float* __restrict__ temperature, float* __restrict__ ADJ)
{
    __shared__ union { __bf16 lH[64*256]; float h2[64*128]; } u;   // 32KB, reused
    __shared__ __bf16 lW[128*256];                                  // 64KB
    __shared__ float  redS[64][4];
    __shared__ float  redQ[64][4];
    __shared__ float  lw3[256];

    const int tid  = threadIdx.x;
    const int wid  = tid >> 6;
    const int lane = tid & 63;
    const int l15  = lane & 15;
    const int lg   = lane >> 4;
    const int wm   = wid >> 2, wn = wid & 3;
    const int mBase = blockIdx.x * 64;

    {   // stage H1 tile (64x256) and W2T (128x256), both XOR-swizzled
        int r0 = tid >> 5;            // 0..15
        int c8 = (tid & 31) * 8;      // 0..248
        int swz = c8 ^ ((r0 & 7) << 3);
#pragma unroll
        for (int i = 0; i < 4; ++i){
            int row = r0 + i*16;
            bf16x8 v = *(const bf16x8*)&H1[(size_t)(mBase+row)*256 + c8];
            *(bf16x8*)&u.lH[row*256 + swz] = v;
        }
#pragma unroll
        for (int i = 0; i < 8; ++i){
            int row = r0 + i*16;
            bf16x8 v = *(const bf16x8*)&W2T[(size_t)row*256 + c8];
            *(bf16x8*)&lW[row*256 + swz] = v;
        }
        if (tid < 256) lw3[tid] = W3[tid];
    }
    __syncthreads();

    f32x4 acc[2][2] = {};
#pragma unroll
    for (int kk = 0; kk < 8; ++kk){
        const int kcol = kk*32 + lg*8;
        bf16x8 av[2], bv[2];
#pragma unroll
        for (int m = 0; m < 2; ++m){
            int row = wm*32 + m*16 + l15;
            av[m] = *(const bf16x8*)&u.lH[row*256 + (kcol ^ ((row&7)<<3))];
        }
#pragma unroll
        for (int n = 0; n < 2; ++n){
            int row = wn*32 + n*16 + l15;
            bv[n] = *(const bf16x8*)&lW[row*256 + (kcol ^ ((row&7)<<3))];
        }
#pragma unroll
        for (int m = 0; m < 2; ++m)
#pragma unroll
            for (int n = 0; n < 2; ++n)
                acc[m][n] = MFMA16(av[m], bv[n], acc[m][n]);
    }

    float b2_[2], g2_[2], be_[2];
#pragma unroll
    for (int n = 0; n < 2; ++n){
        int col = wn*32 + n*16 + l15;
        b2_[n] = b2[col]; g2_[n] = g2[col]; be_[n] = be2[col];
    }
#pragma unroll
    for (int m = 0; m < 2; ++m)
#pragma unroll
        for (int n = 0; n < 2; ++n)
#pragma unroll
            for (int r = 0; r < 4; ++r)
                acc[m][n][r] += b2_[n];

#pragma unroll
    for (int m = 0; m < 2; ++m)
#pragma unroll
        for (int r = 0; r < 4; ++r){
            float s = 0.f, q = 0.f;
#pragma unroll
            for (int n = 0; n < 2; ++n){ float v = acc[m][n][r]; s += v; q += v*v; }
#pragma unroll
            for (int off = 1; off <= 8; off <<= 1){
                s += __shfl_xor(s, off, 64);
                q += __shfl_xor(q, off, 64);
            }
            int row = wm*32 + m*16 + lg*4 + r;
            if (l15 == 0){ redS[row][wn] = s; redQ[row][wn] = q; }
        }
    __syncthreads();   // also: all lH reads done -> safe to overwrite with h2

#pragma unroll
    for (int m = 0; m < 2; ++m)
#pragma unroll
        for (int r = 0; r < 4; ++r){
            int row = wm*32 + m*16 + lg*4 + r;
            float su = redS[row][0]+redS[row][1]+redS[row][2]+redS[row][3];
            float qu = redQ[row][0]+redQ[row][1]+redQ[row][2]+redQ[row][3];
            float mu  = su * (1.f/128.f);
            float var = qu * (1.f/128.f) - mu*mu;
            float rs  = rsqrtf(var + 1e-5f);
#pragma unroll
            for (int n = 0; n < 2; ++n){
                int col = wn*32 + n*16 + l15;
                float x = acc[m][n][r];
                float h = gelu_exact((x - mu)*rs*g2_[n] + be_[n]);
                u.h2[row*128 + (col ^ (row & 31))] = h;
            }
        }
    __syncthreads();

    if (tid < 64){
        const int row = tid;
        const int g = mBase + row;
        float a0 = b3[0], a1 = b3[1];
        for (int k = 0; k < 128; ++k){
            float v = u.h2[row*128 + (k ^ (row & 31))];
            a0 += v * lw3[2*k];
            a1 += v * lw3[2*k+1];
        }
        float t = fmaxf(temperature[0], 0.1f);
        float adj0 = tanhf(a0) * 0.1f;
        float adj1 = tanhf(a1) * 0.1f;
        bool crit = labels[g] > 0;
        float base0 = crit ? 0.25f : 0.75f;
        float base1 = crit ? 0.75f : 0.25f;
        float L0 = (base0 + adj0) / t, L1 = (base1 + adj1) / t;
        float mm = fmaxf(L0, L1);
        float e0 = expf(L0 - mm), e1 = expf(L1 - mm);
        float inv = 1.f / (e0 + e1);
        ADJ[(size_t)g*2    ] = e0 * inv;
        ADJ[(size_t)g*2 + 1] = e1 * inv;
    }
}

// ---------- K3: EMA as a 128-tap truncated convolution (0.9^128 ~ 1.4e-6) ----------
__global__ void ema_kernel(const float* __restrict__ ADJ, float* __restrict__ out)
{
    __shared__ float wtab[128];
    __shared__ float abuf[384*2];
    const int b     = blockIdx.x >> 2;
    const int chunk = blockIdx.x & 3;
    const int c0    = chunk * 256;
    const int tid   = threadIdx.x;
    if (tid < 128) wtab[tid] = powf(0.9f, (float)tid);
    for (int idx = tid; idx < 768; idx += 256){
        int tt = c0 - 128 + (idx >> 1);
        int cc = idx & 1;
        abuf[idx] = (tt >= 0) ? ADJ[((size_t)b*1024 + tt)*2 + cc] : 0.f;
    }
    __syncthreads();
#pragma unroll
    for (int i = 0; i < 2; ++i){
        int item = tid + i*256;
        int tl = item >> 1, cc = item & 1;
        int t = c0 + tl;
        int kmax = min(t, 127);
        float sum = 0.f;
        for (int k = 0; k <= kmax; ++k){
            float coef = (t - k == 0) ? wtab[k] : 0.1f * wtab[k];
            sum += coef * abuf[(tl - k + 128)*2 + cc];
        }
        out[((size_t)b*1024 + t)*2 + cc] = sum;
    }
}

extern "C" void kernel_launch(void* const* d_in, const int* in_sizes, int n_in,
                              void* d_out, int out_size, void* d_ws, size_t ws_size,
                              hipStream_t stream)
{
    const int*   labels = (const int*)  d_in[0];
    const float* X      = (const float*)d_in[1];
    const float* W1     = (const float*)d_in[2];
    const float* b1     = (const float*)d_in[3];
    const float* g1     = (const float*)d_in[4];
    const float* be1    = (const float*)d_in[5];
    const float* W2     = (const float*)d_in[6];
    const float* b2     = (const float*)d_in[7];
    const float* g2     = (const float*)d_in[8];
    const float* be2    = (const float*)d_in[9];
    const float* W3     = (const float*)d_in[10];
    const float* b3     = (const float*)d_in[11];
    const float* temp   = (const float*)d_in[12];
    float* out = (float*)d_out;

    char* ws = (char*)d_ws;
    __bf16* W1T = (__bf16*)(ws);                 // 256 x 2048 bf16  (1 MiB)
    __bf16* W2T = (__bf16*)(ws + 1048576);       // 128 x 256  bf16  (64 KiB)
    __bf16* H1  = (__bf16*)(ws + 1114112);       // 16384 x 256 bf16 (8 MiB)
    float*  ADJ = (float*)(ws + 9502720);        // 16384 x 2 f32    (128 KiB)

    transp_bf16<<<256, 256, 0, stream>>>(W1, W1T, 2048, 256);
    transp_bf16<<<32,  256, 0, stream>>>(W2, W2T, 256, 128);
    gemm1_ln_gelu<<<256, 512, 0, stream>>>(X, W1T, b1, g1, be1, H1);
    tail_fused<<<256, 512, 0, stream>>>(H1, W2T, b2, g2, be2, W3, b3, labels, temp, ADJ);
    ema_kernel<<<64, 256, 0, stream>>>(ADJ, out);
}